// Round 16
// baseline (2137.019 us; speedup 1.0000x reference)
//
#include <hip/hip_runtime.h>
#include <hip/hip_bf16.h>

#define B_ 2
#define S_ 1024
#define E_ 1024
#define NHEAD 16
#define NE 8
#define II 4096
#define KD 1536
#define CLIP_ 768
#define TOK (B_*S_)

typedef short bf16x8 __attribute__((ext_vector_type(8)));
typedef float f32x4 __attribute__((ext_vector_type(4)));

__device__ __forceinline__ float siluf(float x){ return x/(1.f+expf(-x)); }
__device__ __forceinline__ float geluf(float x){
    float x3 = x*x*x;
    return 0.5f*x*(1.f+tanhf(0.7978845608028654f*(x+0.044715f*x3)));
}
__device__ __forceinline__ unsigned short h16(float x){
    union { __hip_bfloat16 b; unsigned short u; } c;
    c.b = __float2bfloat16(x);
    return c.u;
}
__device__ __forceinline__ unsigned pk2(float a, float b){
    return (unsigned)h16(a) | ((unsigned)h16(b)<<16);
}
__device__ __forceinline__ void sp(float a, unsigned& hb, unsigned& lb){
    unsigned short h = h16(a);
    float r = a - __uint_as_float(((unsigned)h)<<16);
    hb = h; lb = h16(r);
}

union U8 { unsigned u[4]; bf16x8 v; uint4 q; };

// ---------------- patch embed ----------------
__global__ void k_patch_embed(const float* __restrict__ x, const float* __restrict__ cw,
                              const float* __restrict__ cb, const float* __restrict__ pos,
                              float* __restrict__ xt){
    int token = blockIdx.x;
    int b = token >> 10, n = token & 1023;
    int hh = n >> 5, ww = n & 31;
    __shared__ float patch[16];
    int tid = threadIdx.x;
    if (tid < 16){
        int c = tid >> 2, py = (tid >> 1) & 1, px = tid & 1;
        patch[tid] = x[(((size_t)b*4 + c)*64 + hh*2+py)*64 + ww*2+px];
    }
    __syncthreads();
    for (int e = tid; e < E_; e += 256){
        float acc = cb[e];
        #pragma unroll
        for (int j=0;j<16;j++) acc += patch[j]*cw[e*16+j];
        xt[(size_t)token*E_ + e] = acc + pos[(size_t)n*E_ + e];
    }
}

// ---------------- timestep MLP ----------------
__global__ void k_time_mlp(const float* __restrict__ t,
                           const float* __restrict__ w1, const float* __restrict__ b1,
                           const float* __restrict__ w2, const float* __restrict__ b2,
                           float* __restrict__ te2g){
    int b = blockIdx.x, tid = threadIdx.x;
    __shared__ float te[256], h1[256];
    if (tid < 128){
        float f = expf((float)tid * (-9.210340371976184f/127.f));
        float a = t[b]*f;
        te[tid]     = sinf(a);
        te[tid+128] = cosf(a);
    }
    __syncthreads();
    {
        float acc = b1[tid];
        const float* wr = w1 + (size_t)tid*256;
        for (int k=0;k<256;k++) acc += te[k]*wr[k];
        h1[tid] = siluf(acc);
    }
    __syncthreads();
    {
        float acc = b2[tid];
        const float* wr = w2 + (size_t)tid*256;
        for (int k=0;k<256;k++) acc += h1[k]*wr[k];
        te2g[b*256+tid] = acc;
    }
}

// ---------------- cond projection ----------------
__global__ void k_cond(const float* __restrict__ te2g, const float* __restrict__ clip,
                       const float* __restrict__ cw, const float* __restrict__ cb,
                       float* __restrict__ silu_c){
    int idx = blockIdx.x*4 + (threadIdx.x>>6);
    int lane = threadIdx.x & 63;
    int b = idx >> 10, e = idx & 1023;
    const float* wr = cw + (size_t)e*1024;
    float acc = 0.f;
    for (int k=lane; k<1024; k+=64){
        float xv = (k<256)? te2g[b*256+k] : clip[b*CLIP_ + k-256];
        acc += xv*wr[k];
    }
    #pragma unroll
    for (int off=32; off; off>>=1) acc += __shfl_down(acc,off);
    if (lane==0) silu_c[b*E_+e] = siluf(acc + cb[e]);
}

// ---------------- adaLN ----------------
__global__ void k_ada2(const float* __restrict__ sic, const float* __restrict__ aw,
                       const float* __restrict__ ab, float* __restrict__ pr){
    int row = blockIdx.x*4 + (threadIdx.x>>6);
    int lane = threadIdx.x & 63;
    const float* w = aw + (size_t)row*1024;
    float a0 = 0.f, a1 = 0.f;
    #pragma unroll
    for (int it=0; it<4; it++){
        int k = it*256 + lane*4;
        float4 wv = *(const float4*)(w+k);
        float4 x0 = *(const float4*)(sic+k);
        float4 x1 = *(const float4*)(sic+1024+k);
        a0 += wv.x*x0.x + wv.y*x0.y + wv.z*x0.z + wv.w*x0.w;
        a1 += wv.x*x1.x + wv.y*x1.y + wv.z*x1.z + wv.w*x1.w;
    }
    #pragma unroll
    for (int off=32; off; off>>=1){ a0 += __shfl_down(a0,off); a1 += __shfl_down(a1,off); }
    if (lane==0){
        float bb = ab[row];
        pr[row] = a0 + bb;
        pr[9*E_ + row] = a1 + bb;
    }
}

// ---------------- LN + modulate -> plain row-major planes (+ optional fp32) ----------------
__global__ void k_ln_mod(const float* __restrict__ src, float* __restrict__ dst32,
                         unsigned short* __restrict__ dsth, unsigned short* __restrict__ dstl,
                         const float* __restrict__ pr, int shc, int scc){
    int token = blockIdx.x, tid = threadIdx.x;
    int b = token >> 10;
    const float* row = src + (size_t)token*E_;
    float4 v = *(const float4*)(row + tid*4);
    float s = v.x+v.y+v.z+v.w;
    float ss = v.x*v.x+v.y*v.y+v.z*v.z+v.w*v.w;
    #pragma unroll
    for (int off=32; off; off>>=1){ s += __shfl_down(s,off); ss += __shfl_down(ss,off); }
    __shared__ float rs_[4], rss_[4];
    int wid = tid >> 6;
    if ((tid&63)==0){ rs_[wid]=s; rss_[wid]=ss; }
    __syncthreads();
    s  = rs_[0]+rs_[1]+rs_[2]+rs_[3];
    ss = rss_[0]+rss_[1]+rss_[2]+rss_[3];
    float mean = s*(1.f/1024.f);
    float rstd = rsqrtf(ss*(1.f/1024.f) - mean*mean + 1e-6f);
    const float* shv = pr + b*9*E_ + shc*E_;
    const float* scv = pr + b*9*E_ + scc*E_;
    int e = tid*4;
    float o[4];
    float4 sc4 = *(const float4*)(scv+e);
    float4 sh4 = *(const float4*)(shv+e);
    o[0] = (v.x-mean)*rstd*(1.f+sc4.x) + sh4.x;
    o[1] = (v.y-mean)*rstd*(1.f+sc4.y) + sh4.y;
    o[2] = (v.z-mean)*rstd*(1.f+sc4.z) + sh4.z;
    o[3] = (v.w-mean)*rstd*(1.f+sc4.w) + sh4.w;
    if (dst32) *(float4*)(dst32 + (size_t)token*E_ + e) = make_float4(o[0],o[1],o[2],o[3]);
    unsigned hu[2], lu[2];
    {
        unsigned h0,l0,h1,l1;
        sp(o[0],h0,l0); sp(o[1],h1,l1);
        hu[0]=h0|(h1<<16); lu[0]=l0|(l1<<16);
        sp(o[2],h0,l0); sp(o[3],h1,l1);
        hu[1]=h0|(h1<<16); lu[1]=l0|(l1<<16);
    }
    *(uint2*)(dsth + (size_t)token*E_ + e) = make_uint2(hu[0],hu[1]);
    *(uint2*)(dstl + (size_t)token*E_ + e) = make_uint2(lu[0],lu[1]);
}

// ---------------- one-shot fp32 -> hi/lo plane split (qwen) ----------------
__global__ void k_split4(const float* __restrict__ src, unsigned short* __restrict__ hp,
                         unsigned short* __restrict__ lp, int n4){
    int i = blockIdx.x*256 + threadIdx.x;
    if (i >= n4) return;
    float4 v = *(const float4*)(src + i*4);
    unsigned h0,l0,h1,l1,h2,l2,h3,l3;
    sp(v.x,h0,l0); sp(v.y,h1,l1); sp(v.z,h2,l2); sp(v.w,h3,l3);
    *(uint2*)(hp + i*4) = make_uint2(h0|(h1<<16), h2|(h3<<16));
    *(uint2*)(lp + i*4) = make_uint2(l0|(l1<<16), l2|(l3<<16));
}

// ================= split-bf16 MFMA GEMM ([128][40] LDS, reg dbuf, M-loop weight reuse) =================
// A: pre-split row-major bf16 planes. B: fp32 weights, convert on stage.
// EPI: 0 fp32; 1 xt+=g*v; 2 gelu->plane(s) at slot rows; 3 slot fp32 (atomic if SPLITK>1);
//      4 SA-QKV (Q fp32 / K planes / V interleaved); 5 CA-K planes; 6 CA-V interleaved
template<int MOE, int EPI, int GATHER, int TERMS, int SPLITK=1>
__global__ __launch_bounds__(256) void k_mm(
    const unsigned short* __restrict__ Ahpp, const unsigned short* __restrict__ Alpp, int lda,
    const float* __restrict__ Wp, int ldw,
    const float* __restrict__ biasp, int bstride,
    void* __restrict__ Cp, void* __restrict__ Cp2, void* __restrict__ Cp3, void* __restrict__ Cp4,
    int ldc, int M, int N, int K,
    const float* __restrict__ pr, int gch,
    const int* __restrict__ cnt, const int* __restrict__ offs,
    const int* __restrict__ list)
{
    constexpr int NPL = (TERMS==3) ? 2 : 1;
    int e  = MOE ? blockIdx.z : 0;
    int Mm = MOE ? cnt[e] : M;
    int o0 = MOE ? offs[e] : 0;
    int nt = gridDim.x / SPLITK;
    int ntile = blockIdx.x % nt;
    int kc0 = blockIdx.x / nt;
    int bn = ntile*128;
    int kbeg = kc0*(K/SPLITK), kend = kbeg + K/SPLITK;
    const float* bias = biasp + (size_t)e*bstride;

    __shared__ __align__(16) unsigned short As_[2][NPL][128*40];
    __shared__ __align__(16) unsigned short Bs_[2][NPL][128*40];

    int tid = threadIdx.x;
    int lane = tid & 63, wid = tid >> 6;
    int wm = wid >> 1, wn = wid & 1;

    int srow = tid >> 1, shalf = tid & 1;
    int sbase = srow*40 + shalf*16;
    const float* Bf = Wp + (size_t)e*N*ldw + (size_t)(bn + srow)*ldw + shalf*16;
    const unsigned short* Ahp = nullptr;
    const unsigned short* Alp = nullptr;

    float fB[16];
    uint4 aH0, aH1, aL0, aL1;

    auto LOAD = [&](int k0){
        aH0 = *(const uint4*)(Ahp+k0);
        aH1 = *(const uint4*)(Ahp+k0+8);
        if (TERMS==3){
            aL0 = *(const uint4*)(Alp+k0);
            aL1 = *(const uint4*)(Alp+k0+8);
        }
        *(float4*)(fB+0)  = *(const float4*)(Bf+k0+0);
        *(float4*)(fB+4)  = *(const float4*)(Bf+k0+4);
        *(float4*)(fB+8)  = *(const float4*)(Bf+k0+8);
        *(float4*)(fB+12) = *(const float4*)(Bf+k0+12);
    };
    auto STAGE = [&](int buf){
        *(uint4*)&As_[buf][0][sbase]   = aH0;
        *(uint4*)&As_[buf][0][sbase+8] = aH1;
        if (TERMS==3){
            *(uint4*)&As_[buf][NPL-1][sbase]   = aL0;
            *(uint4*)&As_[buf][NPL-1][sbase+8] = aL1;
        }
        if (TERMS==3){
            unsigned hb2[8], lb2[8];
            #pragma unroll
            for (int i=0;i<8;i++){
                unsigned h0,l0,h1,l1;
                sp(fB[2*i],h0,l0); sp(fB[2*i+1],h1,l1);
                hb2[i]=h0|(h1<<16); lb2[i]=l0|(l1<<16);
            }
            *(uint4*)&Bs_[buf][0][sbase]   = make_uint4(hb2[0],hb2[1],hb2[2],hb2[3]);
            *(uint4*)&Bs_[buf][0][sbase+8] = make_uint4(hb2[4],hb2[5],hb2[6],hb2[7]);
            *(uint4*)&Bs_[buf][NPL-1][sbase]   = make_uint4(lb2[0],lb2[1],lb2[2],lb2[3]);
            *(uint4*)&Bs_[buf][NPL-1][sbase+8] = make_uint4(lb2[4],lb2[5],lb2[6],lb2[7]);
        } else {
            unsigned hb2[8];
            #pragma unroll
            for (int i=0;i<8;i++) hb2[i] = pk2(fB[2*i],fB[2*i+1]);
            *(uint4*)&Bs_[buf][0][sbase]   = make_uint4(hb2[0],hb2[1],hb2[2],hb2[3]);
            *(uint4*)&Bs_[buf][0][sbase+8] = make_uint4(hb2[4],hb2[5],hb2[6],hb2[7]);
        }
    };

    int fr = lane & 15, fko = (lane>>4)*8, fr4 = (lane>>4)*4;

    for (int mt = blockIdx.y; mt*128 < Mm; mt += gridDim.y){
        int bm = mt*128;
        {
            int amr = bm + srow; if (amr >= Mm) amr = Mm - 1;
            int arow;
            if (MOE) arow = GATHER ? list[o0 + amr] : (o0 + amr);
            else     arow = amr;
            Ahp = Ahpp + (size_t)arow*lda + shalf*16;
            Alp = (TERMS==3) ? (Alpp + (size_t)arow*lda + shalf*16) : nullptr;
        }

        f32x4 acc[4][4];
        #pragma unroll
        for (int m=0;m<4;m++)
            #pragma unroll
            for (int n=0;n<4;n++) acc[m][n] = (f32x4){0.f,0.f,0.f,0.f};

        LOAD(kbeg);
        STAGE(0);
        __syncthreads();
        int cur = 0;
        for (int k0=kbeg; k0<kend; k0+=32){
            bool nxt = (k0+32) < kend;
            if (nxt) LOAD(k0+32);          // issue next-chunk loads early (hide under MFMA)
            bf16x8 ah[4], bh[4], al[4], bl[4];
            #pragma unroll
            for (int m=0;m<4;m++){
                int off = (wm*64 + m*16 + fr)*40 + fko;
                ah[m] = *(const bf16x8*)&As_[cur][0][off];
                if (TERMS==3) al[m] = *(const bf16x8*)&As_[cur][NPL-1][off];
            }
            #pragma unroll
            for (int n=0;n<4;n++){
                int off = (wn*64 + n*16 + fr)*40 + fko;
                bh[n] = *(const bf16x8*)&Bs_[cur][0][off];
                if (TERMS==3) bl[n] = *(const bf16x8*)&Bs_[cur][NPL-1][off];
            }
            #pragma unroll
            for (int m=0;m<4;m++)
                #pragma unroll
                for (int n=0;n<4;n++){
                    acc[m][n] = __builtin_amdgcn_mfma_f32_16x16x32_bf16(ah[m], bh[n], acc[m][n], 0, 0, 0);
                    if (TERMS==3){
                        acc[m][n] = __builtin_amdgcn_mfma_f32_16x16x32_bf16(ah[m], bl[n], acc[m][n], 0, 0, 0);
                        acc[m][n] = __builtin_amdgcn_mfma_f32_16x16x32_bf16(al[m], bh[n], acc[m][n], 0, 0, 0);
                    }
                }
            if (nxt) STAGE(cur^1);         // write the other buffer after compute
            __syncthreads();
            cur ^= 1;
        }

        #pragma unroll
        for (int m=0;m<4;m++){
            #pragma unroll
            for (int j=0;j<4;j++){
                int row = bm + wm*64 + m*16 + fr4 + j;
                if (row >= Mm) continue;
                #pragma unroll
                for (int n=0;n<4;n++){
                    int col = bn + wn*64 + n*16 + fr;
                    float bv = (SPLITK==1 || kc0==0) ? bias[col] : 0.f;
                    float v = acc[m][n][j] + bv;
                    if (EPI==0){
                        ((float*)Cp)[(size_t)row*ldc + col] = v;
                    } else if (EPI==1){
                        int bb = row >> 10;
                        ((float*)Cp)[(size_t)row*ldc + col] += pr[bb*9*E_ + gch*E_ + col] * v;
                    } else if (EPI==2){
                        size_t pi = (size_t)(o0+row)*ldc + col;
                        if (TERMS==3){
                            unsigned hb, lb; sp(geluf(v), hb, lb);
                            ((unsigned short*)Cp )[pi] = (unsigned short)hb;
                            ((unsigned short*)Cp2)[pi] = (unsigned short)lb;
                        } else {
                            ((unsigned short*)Cp )[pi] = h16(geluf(v));
                        }
                    } else if (EPI==3){
                        if (SPLITK==1)
                            ((float*)Cp)[(size_t)(o0+row)*ldc + col] = v;
                        else
                            atomicAdd(&((float*)Cp)[(size_t)(o0+row)*ldc + col], v);
                    } else if (EPI==4){
                        if (col < 1024){
                            ((float*)Cp)[(size_t)row*1024 + col] = v;
                        } else {
                            int c2 = col - 1024;
                            int isv = c2 >> 10;
                            int cc = c2 & 1023;
                            int hh2 = cc >> 6, d = cc & 63;
                            size_t idx = (((size_t)(row>>10)*NHEAD + hh2)*1024 + (row & 1023))*64 + d;
                            unsigned hb, lb; sp(v, hb, lb);
                            if (!isv){
                                ((unsigned short*)Cp2)[idx] = (unsigned short)hb;
                                ((unsigned short*)Cp3)[idx] = (unsigned short)lb;
                            } else {
                                ((unsigned*)Cp4)[idx] = hb | (lb<<16);
                            }
                        }
                    } else if (EPI==5){
                        int hh2 = col >> 6, d = col & 63;
                        size_t idx = (((size_t)(row>>8)*NHEAD + hh2)*256 + (row & 255))*64 + d;
                        unsigned hb, lb; sp(v, hb, lb);
                        ((unsigned short*)Cp )[idx] = (unsigned short)hb;
                        ((unsigned short*)Cp2)[idx] = (unsigned short)lb;
                    } else { // EPI==6
                        int hh2 = col >> 6, d = col & 63;
                        size_t idx = (((size_t)(row>>8)*NHEAD + hh2)*256 + (row & 255))*64 + d;
                        unsigned hb, lb; sp(v, hb, lb);
                        ((unsigned*)Cp)[idx] = hb | (lb<<16);
                    }
                }
            }
        }
        __syncthreads();
    }
}

// ================= MFMA flash attention: K/V pre-split, O -> plain row-major planes =================
__global__ __launch_bounds__(256) void k_attn_m(
    const float* __restrict__ qp, int qstride,
    const unsigned short* __restrict__ Khp, const unsigned short* __restrict__ Klp,
    const unsigned* __restrict__ Vip,
    unsigned short* __restrict__ oph, unsigned short* __restrict__ opl,
    int Sq, int Sk, float scale)
{
    __shared__ __align__(16) unsigned short Kh[64*72];
    __shared__ __align__(16) unsigned short Kl[64*72];
    __shared__ __align__(16) unsigned V_i[64*70];
    __shared__ __align__(16) unsigned short P_[4][2][16*72];

    int tid = threadIdx.x, lane = tid & 63, wid = tid >> 6;
    int g = lane >> 4, fr = lane & 15;
    int h = blockIdx.y, b = blockIdx.z;
    int qbase = blockIdx.x*64;
    size_t bhbase = (size_t)(b*NHEAD + h)*Sk*64;

    bf16x8 qh[2], ql[2];
    {
        const float* qr = qp + (size_t)(b*Sq + qbase + wid*16 + fr)*qstride + h*64;
        #pragma unroll
        for (int ds=0; ds<2; ds++){
            float f[8];
            *(float4*)(f+0) = *(const float4*)(qr + ds*32 + g*8);
            *(float4*)(f+4) = *(const float4*)(qr + ds*32 + g*8 + 4);
            U8 uh, ul;
            #pragma unroll
            for (int i=0;i<4;i++){
                unsigned h0,l0,h1,l1;
                sp(f[2*i]*scale, h0,l0); sp(f[2*i+1]*scale, h1,l1);
                uh.u[i] = h0|(h1<<16); ul.u[i] = l0|(l1<<16);
            }
            qh[ds] = uh.v; ql[ds] = ul.v;
        }
    }

    float m_run = -1e30f, l_run = 0.f;
    f32x4 oacc[4];
    #pragma unroll
    for (int dt=0;dt<4;dt++) oacc[dt] = (f32x4){0.f,0.f,0.f,0.f};

    unsigned short* PhW = &P_[wid][0][0];
    unsigned short* PlW = &P_[wid][1][0];

    for (int kt0 = 0; kt0 < Sk; kt0 += 64){
        __syncthreads();
        {
            int srow = tid >> 2, d0 = (tid & 3) << 4;
            size_t gidx = bhbase + (size_t)(kt0 + srow)*64 + d0;
            int base = srow*72 + d0;
            *(uint4*)&Kh[base]   = *(const uint4*)(Khp + gidx);
            *(uint4*)&Kh[base+8] = *(const uint4*)(Khp + gidx + 8);
            *(uint4*)&Kl[base]   = *(const uint4*)(Klp + gidx);
            *(uint4*)&Kl[base+8] = *(const uint4*)(Klp + gidx + 8);
            const unsigned* vsrc = Vip + gidx;
            int vb = srow*70 + d0;
            #pragma unroll
            for (int i4=0;i4<4;i4++){
                uint4 u = *(const uint4*)(vsrc + i4*4);
                *(uint2*)&V_i[vb + i4*4]     = make_uint2(u.x,u.y);
                *(uint2*)&V_i[vb + i4*4 + 2] = make_uint2(u.z,u.w);
            }
        }
        __syncthreads();

        f32x4 st[4];
        #pragma unroll
        for (int kt=0;kt<4;kt++) st[kt] = (f32x4){0.f,0.f,0.f,0.f};
        #pragma unroll
        for (int ds=0; ds<2; ds++){
            #pragma unroll
            for (int kt=0;kt<4;kt++){
                int row = kt*16 + fr;
                int so = row*72 + ds*32 + g*8;
                bf16x8 kh  = *(const bf16x8*)&Kh[so];
                bf16x8 klo = *(const bf16x8*)&Kl[so];
                st[kt] = __builtin_amdgcn_mfma_f32_16x16x32_bf16(kh, qh[ds], st[kt], 0,0,0);
                st[kt] = __builtin_amdgcn_mfma_f32_16x16x32_bf16(kh, ql[ds], st[kt], 0,0,0);
                st[kt] = __builtin_amdgcn_mfma_f32_16x16x32_bf16(klo, qh[ds], st[kt], 0,0,0);
            }
        }

        float pmax = -1e30f;
        #pragma unroll
        for (int kt=0;kt<4;kt++)
            #pragma unroll
            for (int r=0;r<4;r++) pmax = fmaxf(pmax, st[kt][r]);
        pmax = fmaxf(pmax, __shfl_xor(pmax, 16));
        pmax = fmaxf(pmax, __shfl_xor(pmax, 32));
        float mnew = fmaxf(m_run, pmax);
        float p[4][4]; float psum = 0.f;
        #pragma unroll
        for (int kt=0;kt<4;kt++)
            #pragma unroll
            for (int r=0;r<4;r++){ float pv = expf(st[kt][r] - mnew); p[kt][r] = pv; psum += pv; }
        psum += __shfl_xor(psum, 16);
        psum += __shfl_xor(psum, 32);
        float corr = expf(m_run - mnew);
        l_run = l_run*corr + psum;
        m_run = mnew;
        #pragma unroll
        for (int j=0;j<4;j++){
            float cj = __shfl(corr, g*4 + j);
            #pragma unroll
            for (int dt=0;dt<4;dt++) oacc[dt][j] *= cj;
        }

        #pragma unroll
        for (int kt=0;kt<4;kt++){
            unsigned h0,l0,h1,l1,h2,l2,h3,l3;
            sp(p[kt][0],h0,l0); sp(p[kt][1],h1,l1);
            sp(p[kt][2],h2,l2); sp(p[kt][3],h3,l3);
            int base = fr*72 + kt*16 + g*4;
            *(unsigned*)&PhW[base]     = h0|(h1<<16);
            *(unsigned*)&PhW[base + 2] = h2|(h3<<16);
            *(unsigned*)&PlW[base]     = l0|(l1<<16);
            *(unsigned*)&PlW[base + 2] = l2|(l3<<16);
        }

        #pragma unroll
        for (int ks=0; ks<2; ks++){
            int pso = fr*72 + ks*32 + g*8;
            bf16x8 ph = *(const bf16x8*)&PhW[pso];
            bf16x8 pl = *(const bf16x8*)&PlW[pso];
            #pragma unroll
            for (int dt=0; dt<4; dt++){
                unsigned w[8];
                #pragma unroll
                for (int j=0;j<8;j++){
                    int row = ks*32 + g*8 + j;
                    w[j] = V_i[row*70 + dt*16 + fr];
                }
                U8 vh, vl;
                #pragma unroll
                for (int i=0;i<4;i++){
                    vh.u[i] = (w[2*i] & 0xffffu) | (w[2*i+1] << 16);
                    vl.u[i] = (w[2*i] >> 16)     | (w[2*i+1] & 0xffff0000u);
                }
                oacc[dt] = __builtin_amdgcn_mfma_f32_16x16x32_bf16(ph, vh.v, oacc[dt], 0,0,0);
                oacc[dt] = __builtin_amdgcn_mfma_f32_16x16x32_bf16(ph, vl.v, oacc[dt], 0,0,0);
                oacc[dt] = __builtin_amdgcn_mfma_f32_16x16x32_bf16(pl, vh.v, oacc[dt], 0,0,0);
            }
        }
    }

    float linv = 1.f / l_run;
    #pragma unroll
    for (int j=0;j<4;j++){
        float lj = __shfl(linv, g*4 + j);
        int row = qbase + wid*16 + g*4 + j;
        size_t obase = (size_t)(b*Sq + row)*E_ + h*64;
        #pragma unroll
        for (int dt=0;dt<4;dt++){
            unsigned hb, lb; sp(oacc[dt][j]*lj, hb, lb);
            oph[obase + dt*16 + fr] = (unsigned short)hb;
            opl[obase + dt*16 + fr] = (unsigned short)lb;
        }
    }
}

// ---------------- MoE routing ----------------
__global__ void k_route(const float* __restrict__ xn, const float* __restrict__ gw,
                        const float* __restrict__ gb, int* __restrict__ i01,
                        float* __restrict__ w01, int* __restrict__ cnt){
    int token = blockIdx.x, lane = threadIdx.x;
    const float* row = xn + (size_t)token*E_;
    float part[8] = {0,0,0,0,0,0,0,0};
    for (int k = lane; k < E_; k += 64){
        float xv = row[k];
        #pragma unroll
        for (int e=0;e<8;e++) part[e] += xv*gw[e*E_+k];
    }
    #pragma unroll
    for (int e=0;e<8;e++){
        #pragma unroll
        for (int off=32; off; off>>=1) part[e] += __shfl_down(part[e], off);
    }
    if (lane==0){
        float lg[8]; float mx = -1e30f;
        #pragma unroll
        for (int e=0;e<8;e++){ lg[e] = part[e]+gb[e]; if (lg[e]>mx) mx = lg[e]; }
        float sum = 0.f;
        #pragma unroll
        for (int e=0;e<8;e++){ lg[e] = expf(lg[e]-mx); sum += lg[e]; }
        int a0 = 0;
        #pragma unroll
        for (int e=1;e<8;e++) if (lg[e] > lg[a0]) a0 = e;
        int a1 = (a0==0)?1:0;
        #pragma unroll
        for (int e=0;e<8;e++) if (e!=a0 && lg[e] > lg[a1]) a1 = e;
        float p0 = lg[a0]/sum, p1 = lg[a1]/sum;
        float inv = 1.f/(p0+p1+1e-6f);
        i01[token*2+0]=a0; i01[token*2+1]=a1;
        w01[token*2+0]=p0*inv; w01[token*2+1]=p1*inv;
        atomicAdd(&cnt[a0],1); atomicAdd(&cnt[a1],1);
    }
}

__global__ void k_scan(const int* __restrict__ cnt, int* __restrict__ offs, int* __restrict__ curs){
    if (threadIdx.x==0 && blockIdx.x==0){
        int o = 0;
        for (int e=0;e<8;e++){ offs[e]=o; curs[e]=o; o += cnt[e]; }
    }
}

__global__ void k_place(const int* __restrict__ i01,
                        int* __restrict__ curs, int* __restrict__ list,
                        int* __restrict__ t2s){
    int t = blockIdx.x*256 + threadIdx.x;
    if (t >= TOK) return;
    #pragma unroll
    for (int s=0;s<2;s++){
        int e = i01[t*2+s];
        int p = atomicAdd(&curs[e],1);
        list[p] = t;
        t2s[t*2+s] = p;
    }
}

__global__ void k_moe_combine2(float* __restrict__ xt, const float* __restrict__ yslot,
                               const int* __restrict__ t2s, const float* __restrict__ w01,
                               const float* __restrict__ pr){
    int idx = blockIdx.x*256 + threadIdx.x;
    int token = idx >> 10, n = idx & 1023;
    int b = token >> 10;
    int s0 = t2s[token*2], s1 = t2s[token*2+1];
    float mo = w01[token*2]*yslot[(size_t)s0*E_+n] + w01[token*2+1]*yslot[(size_t)s1*E_+n];
    xt[idx] += pr[b*9*E_ + 8*E_ + n]*mo;
}

// ---------------- final LN + projection + unpatchify ----------------
__global__ void k_final(const float* __restrict__ xt, const float* __restrict__ fw,
                        const float* __restrict__ fb, float* __restrict__ out){
    int token = blockIdx.x, tid = threadIdx.x;
    int b = token >> 10, n = token & 1023, hh = n >> 5, ww = n & 31;
    const float* row = xt + (size_t)token*E_;
    float4 v = *(const float4*)(row + tid*4);
    float s = v.x+v.y+v.z+v.w;
    float ss = v.x*v.x+v.y*v.y+v.z*v.z+v.w*v.w;
    #pragma unroll
    for (int off=32; off; off>>=1){ s += __shfl_down(s,off); ss += __shfl_down(ss,off); }
    __shared__ float rs_[4], rss_[4];
    int wid = tid >> 6;
    if ((tid&63)==0){ rs_[wid]=s; rss_[wid]=ss; }
    __syncthreads();
    s  = rs_[0]+rs_[1]+rs_[2]+rs_[3];
    ss = rss_[0]+rss_[1]+rss_[2]+rss_[3];
    float mean = s*(1.f/1024.f);
    float rstd = rsqrtf(ss*(1.f/1024.f) - mean*mean + 1e-6f);
    __shared__ float xl[1024];
    int e = tid*4;
    xl[e+0]=(v.x-mean)*rstd; xl[e+1]=(v.y-mean)*rstd;
    xl[e+2]=(v.z-mean)*rstd; xl[e+3]=(v.w-mean)*rstd;
    __syncthreads();
    int o = tid & 15, seg = tid >> 4;
    float part = 0.f;
    const float* wr = fw + (size_t)o*E_ + seg*64;
    const float* xr = xl + seg*64;
    #pragma unroll 8
    for (int j=0;j<64;j++) part += xr[j]*wr[j];
    __shared__ float ps[16][17];
    ps[seg][o] = part;
    __syncthreads();
    if (tid < 16){
        float acc = fb[tid];
        #pragma unroll
        for (int s2=0;s2<16;s2++) acc += ps[s2][tid];
        int py = tid>>3, px = (tid>>2)&1, ch = tid&3;
        out[(((size_t)b*4+ch)*64 + hh*2+py)*64 + ww*2+px] = acc;
    }
}

extern "C" void kernel_launch(void* const* d_in, const int* in_sizes, int n_in,
                              void* d_out, int out_size, void* d_ws, size_t ws_size,
                              hipStream_t stream){
    const float* x        = (const float*)d_in[0];
    const float* t        = (const float*)d_in[1];
    const float* clip     = (const float*)d_in[2];
    const float* qwen     = (const float*)d_in[3];
    const float* conv_w   = (const float*)d_in[4];
    const float* conv_b   = (const float*)d_in[5];
    const float* pos      = (const float*)d_in[6];
    const float* tw1      = (const float*)d_in[7];
    const float* tb1      = (const float*)d_in[8];
    const float* tw2      = (const float*)d_in[9];
    const float* tb2      = (const float*)d_in[10];
    const float* cond_w   = (const float*)d_in[11];
    const float* cond_b   = (const float*)d_in[12];
    const float* ada_w    = (const float*)d_in[13];
    const float* ada_b    = (const float*)d_in[14];
    const float* sa_in_w  = (const float*)d_in[15];
    const float* sa_in_b  = (const float*)d_in[16];
    const float* sa_out_w = (const float*)d_in[17];
    const float* sa_out_b = (const float*)d_in[18];
    const float* ca_q_w   = (const float*)d_in[19];
    const float* ca_k_w   = (const float*)d_in[20];
    const float* ca_v_w   = (const float*)d_in[21];
    const float* ca_in_b  = (const float*)d_in[22];
    const float* ca_out_w = (const float*)d_in[23];
    const float* ca_out_b = (const float*)d_in[24];
    const float* gate_w   = (const float*)d_in[25];
    const float* gate_b   = (const float*)d_in[26];
    const float* e_w1     = (const float*)d_in[27];
    const float* e_b1     = (const float*)d_in[28];
    const float* e_w2     = (const float*)d_in[29];
    const float* e_b2     = (const float*)d_in[30];
    const float* fin_w    = (const float*)d_in[31];
    const float* fin_b    = (const float*)d_in[32];

    float* ws    = (float*)d_ws;
    float* xt    = ws;                                         // 2M floats
    float* xn    = ws + 2097152;                               // 2M
    float* qbuf  = ws + 4194304;                               // 2M fp32 (attn Q)
    unsigned short* Khp = (unsigned short*)(ws + 6291456);     // 2M shorts
    unsigned short* Klp = (unsigned short*)(ws + 7340032);
    unsigned*       Vip = (unsigned*)(ws + 8388608);           // 2M u32
    float* yslot = ws + 4194304;                               // MoE phase reuse (4M floats)
    unsigned short* xnh  = (unsigned short*)(ws + 10485760);
    unsigned short* xnl  = (unsigned short*)(ws + 11534336);
    unsigned short* obh  = (unsigned short*)(ws + 12582912);
    unsigned short* obl  = (unsigned short*)(ws + 13631488);
    unsigned short* hidh = (unsigned short*)(ws + 14680064);   // 8M floats region
    unsigned short* hidl = (unsigned short*)(ws + 23068672);
    unsigned short* qwh  = (unsigned short*)(ws + 31457280);
    unsigned short* qwl  = (unsigned short*)(ws + 31981568);
    float* pr    = ws + 33554432;
    float* sic   = ws + 33572864;
    float* w01   = ws + 33574912;
    int*   i01   = (int*)(ws + 33579008);
    int*   t2s   = (int*)(ws + 33583104);
    int*   list  = (int*)(ws + 33587200);
    int*   cnt   = (int*)(ws + 33591296);
    int*   offs  = cnt + 8;
    int*   curs  = cnt + 16;
    float* te2g  = ws + 33591808;

    k_patch_embed<<<TOK,256,0,stream>>>(x, conv_w, conv_b, pos, xt);
    k_time_mlp<<<B_,256,0,stream>>>(t, tw1, tb1, tw2, tb2, te2g);
    k_cond<<<512,256,0,stream>>>(te2g, clip, cond_w, cond_b, sic);
    k_split4<<<(B_*256*KD/4+255)/256,256,0,stream>>>(qwen, qwh, qwl, B_*256*KD/4);

    for (int i=0;i<2;i++){
        k_ada2<<<2304,256,0,stream>>>(sic, ada_w + (size_t)i*9*E_*E_,
                                      ada_b + (size_t)i*9*E_, pr);
        // ---- self-attention ----
        k_ln_mod<<<TOK,256,0,stream>>>(xt, nullptr, xnh, xnl, pr, 0, 1);
        k_mm<0,4,0,3><<<dim3(24,16),256,0,stream>>>(
            xnh, xnl, E_, sa_in_w + (size_t)i*3*E_*E_, E_, sa_in_b + (size_t)i*3*E_, 0,
            qbuf, Khp, Klp, Vip, 0, TOK, 3*E_, E_, nullptr, 0, nullptr, nullptr, nullptr);
        k_attn_m<<<dim3(16,NHEAD,B_),256,0,stream>>>(qbuf, 1024, Khp, Klp, Vip,
                                                     obh, obl, S_, S_, 0.125f);
        k_mm<0,1,0,3><<<dim3(8,16),256,0,stream>>>(
            obh, obl, E_, sa_out_w + (size_t)i*E_*E_, E_, sa_out_b + (size_t)i*E_, 0,
            xt, nullptr, nullptr, nullptr, E_, TOK, E_, E_, pr, 2, nullptr, nullptr, nullptr);
        // ---- cross-attention ----
        k_ln_mod<<<TOK,256,0,stream>>>(xt, nullptr, xnh, xnl, pr, 3, 4);
        k_mm<0,0,0,3><<<dim3(8,16),256,0,stream>>>(
            xnh, xnl, E_, ca_q_w + (size_t)i*E_*E_, E_, ca_in_b + (size_t)i*3*E_, 0,
            qbuf, nullptr, nullptr, nullptr, E_, TOK, E_, E_, nullptr, 0, nullptr, nullptr, nullptr);
        k_mm<0,5,0,3><<<dim3(8,4),256,0,stream>>>(
            qwh, qwl, KD, ca_k_w + (size_t)i*E_*KD, KD, ca_in_b + (size_t)i*3*E_ + E_, 0,
            Khp, Klp, nullptr, nullptr, 0, B_*256, E_, KD, nullptr, 0, nullptr, nullptr, nullptr);
        k_mm<0,6,0,3><<<dim3(8,4),256,0,stream>>>(
            qwh, qwl, KD, ca_v_w + (size_t)i*E_*KD, KD, ca_in_b + (size_t)i*3*E_ + 2*E_, 0,
            Vip, nullptr, nullptr, nullptr, 0, B_*256, E_, KD, nullptr, 0, nullptr, nullptr, nullptr);
        k_attn_m<<<dim3(16,NHEAD,B_),256,0,stream>>>(qbuf, E_, Khp, Klp, Vip,
                                                     obh, obl, S_, 256, 0.125f);
        k_mm<0,1,0,3><<<dim3(8,16),256,0,stream>>>(
            obh, obl, E_, ca_out_w + (size_t)i*E_*E_, E_, ca_out_b + (size_t)i*E_, 0,
            xt, nullptr, nullptr, nullptr, E_, TOK, E_, E_, pr, 5, nullptr, nullptr, nullptr);
        // ---- MoE ----
        k_ln_mod<<<TOK,256,0,stream>>>(xt, xn, xnh, xnl, pr, 6, 7);
        hipMemsetAsync(cnt, 0, 8*sizeof(int), stream);
        k_route<<<TOK,64,0,stream>>>(xn, gate_w + (size_t)i*NE*E_, gate_b + (size_t)i*NE,
                                     i01, w01, cnt);
        k_scan<<<1,64,0,stream>>>(cnt, offs, curs);
        k_place<<<TOK/256,256,0,stream>>>(i01, curs, list, t2s);
        hipMemsetAsync(yslot, 0, (size_t)2*TOK*E_*sizeof(float), stream);
        if (i==0){
            k_mm<1,2,1,3><<<dim3(32,2,NE),256,0,stream>>>(
                xnh, xnl, E_, e_w1 + (size_t)i*NE*II*E_, E_, e_b1 + (size_t)i*NE*II, II,
                hidh, hidl, nullptr, nullptr, II, 0, II, E_, nullptr, 0, cnt, offs, list);
            k_mm<1,3,0,3,4><<<dim3(32,2,NE),256,0,stream>>>(
                hidh, hidl, II, e_w2 + (size_t)i*NE*E_*II, II, e_b2 + (size_t)i*NE*E_, E_,
                yslot, nullptr, nullptr, nullptr, E_, 0, E_, II, nullptr, 0, cnt, offs, nullptr);
        } else {
            k_mm<1,2,1,1><<<dim3(32,2,NE),256,0,stream>>>(
                xnh, nullptr, E_, e_w1 + (size_t)i*NE*II*E_, E_, e_b1 + (size_t)i*NE*II, II,
                hidh, nullptr, nullptr, nullptr, II, 0, II, E_, nullptr, 0, cnt, offs, list);
            k_mm<1,3,0,1,4><<<dim3(32,2,NE),256,0,stream>>>(
                hidh, nullptr, II, e_w2 + (size_t)i*NE*E_*II, II, e_b2 + (size_t)i*NE*E_, E_,
                yslot, nullptr, nullptr, nullptr, E_, 0, E_, II, nullptr, 0, cnt, offs, nullptr);
        }
        k_moe_combine2<<<TOK*E_/256,256,0,stream>>>(xt, yslot, t2s, w01, pr);
    }
    k_final<<<TOK,256,0,stream>>>(xt, fin_w, fin_b, (float*)d_out);
}

// Round 17
// 1954.122 us; speedup vs baseline: 1.0936x; 1.0936x over previous
//
#include <hip/hip_runtime.h>
#include <hip/hip_bf16.h>

#define B_ 2
#define S_ 1024
#define E_ 1024
#define NHEAD 16
#define NE 8
#define II 4096
#define KD 1536
#define CLIP_ 768
#define TOK (B_*S_)

typedef short bf16x8 __attribute__((ext_vector_type(8)));
typedef float f32x4 __attribute__((ext_vector_type(4)));

__device__ __forceinline__ float siluf(float x){ return x/(1.f+expf(-x)); }
__device__ __forceinline__ float geluf(float x){
    float x3 = x*x*x;
    return 0.5f*x*(1.f+tanhf(0.7978845608028654f*(x+0.044715f*x3)));
}
__device__ __forceinline__ unsigned short h16(float x){
    union { __hip_bfloat16 b; unsigned short u; } c;
    c.b = __float2bfloat16(x);
    return c.u;
}
__device__ __forceinline__ unsigned pk2(float a, float b){
    return (unsigned)h16(a) | ((unsigned)h16(b)<<16);
}
__device__ __forceinline__ void sp(float a, unsigned& hb, unsigned& lb){
    unsigned short h = h16(a);
    float r = a - __uint_as_float(((unsigned)h)<<16);
    hb = h; lb = h16(r);
}

union U8 { unsigned u[4]; bf16x8 v; uint4 q; };

// ---------------- patch embed ----------------
__global__ void k_patch_embed(const float* __restrict__ x, const float* __restrict__ cw,
                              const float* __restrict__ cb, const float* __restrict__ pos,
                              float* __restrict__ xt){
    int token = blockIdx.x;
    int b = token >> 10, n = token & 1023;
    int hh = n >> 5, ww = n & 31;
    __shared__ float patch[16];
    int tid = threadIdx.x;
    if (tid < 16){
        int c = tid >> 2, py = (tid >> 1) & 1, px = tid & 1;
        patch[tid] = x[(((size_t)b*4 + c)*64 + hh*2+py)*64 + ww*2+px];
    }
    __syncthreads();
    for (int e = tid; e < E_; e += 256){
        float acc = cb[e];
        #pragma unroll
        for (int j=0;j<16;j++) acc += patch[j]*cw[e*16+j];
        xt[(size_t)token*E_ + e] = acc + pos[(size_t)n*E_ + e];
    }
}

// ---------------- timestep MLP ----------------
__global__ void k_time_mlp(const float* __restrict__ t,
                           const float* __restrict__ w1, const float* __restrict__ b1,
                           const float* __restrict__ w2, const float* __restrict__ b2,
                           float* __restrict__ te2g){
    int b = blockIdx.x, tid = threadIdx.x;
    __shared__ float te[256], h1[256];
    if (tid < 128){
        float f = expf((float)tid * (-9.210340371976184f/127.f));
        float a = t[b]*f;
        te[tid]     = sinf(a);
        te[tid+128] = cosf(a);
    }
    __syncthreads();
    {
        float acc = b1[tid];
        const float* wr = w1 + (size_t)tid*256;
        for (int k=0;k<256;k++) acc += te[k]*wr[k];
        h1[tid] = siluf(acc);
    }
    __syncthreads();
    {
        float acc = b2[tid];
        const float* wr = w2 + (size_t)tid*256;
        for (int k=0;k<256;k++) acc += h1[k]*wr[k];
        te2g[b*256+tid] = acc;
    }
}

// ---------------- cond projection ----------------
__global__ void k_cond(const float* __restrict__ te2g, const float* __restrict__ clip,
                       const float* __restrict__ cw, const float* __restrict__ cb,
                       float* __restrict__ silu_c){
    int idx = blockIdx.x*4 + (threadIdx.x>>6);
    int lane = threadIdx.x & 63;
    int b = idx >> 10, e = idx & 1023;
    const float* wr = cw + (size_t)e*1024;
    float acc = 0.f;
    for (int k=lane; k<1024; k+=64){
        float xv = (k<256)? te2g[b*256+k] : clip[b*CLIP_ + k-256];
        acc += xv*wr[k];
    }
    #pragma unroll
    for (int off=32; off; off>>=1) acc += __shfl_down(acc,off);
    if (lane==0) silu_c[b*E_+e] = siluf(acc + cb[e]);
}

// ---------------- adaLN ----------------
__global__ void k_ada2(const float* __restrict__ sic, const float* __restrict__ aw,
                       const float* __restrict__ ab, float* __restrict__ pr){
    int row = blockIdx.x*4 + (threadIdx.x>>6);
    int lane = threadIdx.x & 63;
    const float* w = aw + (size_t)row*1024;
    float a0 = 0.f, a1 = 0.f;
    #pragma unroll
    for (int it=0; it<4; it++){
        int k = it*256 + lane*4;
        float4 wv = *(const float4*)(w+k);
        float4 x0 = *(const float4*)(sic+k);
        float4 x1 = *(const float4*)(sic+1024+k);
        a0 += wv.x*x0.x + wv.y*x0.y + wv.z*x0.z + wv.w*x0.w;
        a1 += wv.x*x1.x + wv.y*x1.y + wv.z*x1.z + wv.w*x1.w;
    }
    #pragma unroll
    for (int off=32; off; off>>=1){ a0 += __shfl_down(a0,off); a1 += __shfl_down(a1,off); }
    if (lane==0){
        float bb = ab[row];
        pr[row] = a0 + bb;
        pr[9*E_ + row] = a1 + bb;
    }
}

// ---------------- LN + modulate -> plain row-major planes (+ optional fp32) ----------------
__global__ void k_ln_mod(const float* __restrict__ src, float* __restrict__ dst32,
                         unsigned short* __restrict__ dsth, unsigned short* __restrict__ dstl,
                         const float* __restrict__ pr, int shc, int scc){
    int token = blockIdx.x, tid = threadIdx.x;
    int b = token >> 10;
    const float* row = src + (size_t)token*E_;
    float4 v = *(const float4*)(row + tid*4);
    float s = v.x+v.y+v.z+v.w;
    float ss = v.x*v.x+v.y*v.y+v.z*v.z+v.w*v.w;
    #pragma unroll
    for (int off=32; off; off>>=1){ s += __shfl_down(s,off); ss += __shfl_down(ss,off); }
    __shared__ float rs_[4], rss_[4];
    int wid = tid >> 6;
    if ((tid&63)==0){ rs_[wid]=s; rss_[wid]=ss; }
    __syncthreads();
    s  = rs_[0]+rs_[1]+rs_[2]+rs_[3];
    ss = rss_[0]+rss_[1]+rss_[2]+rss_[3];
    float mean = s*(1.f/1024.f);
    float rstd = rsqrtf(ss*(1.f/1024.f) - mean*mean + 1e-6f);
    const float* shv = pr + b*9*E_ + shc*E_;
    const float* scv = pr + b*9*E_ + scc*E_;
    int e = tid*4;
    float o[4];
    float4 sc4 = *(const float4*)(scv+e);
    float4 sh4 = *(const float4*)(shv+e);
    o[0] = (v.x-mean)*rstd*(1.f+sc4.x) + sh4.x;
    o[1] = (v.y-mean)*rstd*(1.f+sc4.y) + sh4.y;
    o[2] = (v.z-mean)*rstd*(1.f+sc4.z) + sh4.z;
    o[3] = (v.w-mean)*rstd*(1.f+sc4.w) + sh4.w;
    if (dst32) *(float4*)(dst32 + (size_t)token*E_ + e) = make_float4(o[0],o[1],o[2],o[3]);
    unsigned hu[2], lu[2];
    {
        unsigned h0,l0,h1,l1;
        sp(o[0],h0,l0); sp(o[1],h1,l1);
        hu[0]=h0|(h1<<16); lu[0]=l0|(l1<<16);
        sp(o[2],h0,l0); sp(o[3],h1,l1);
        hu[1]=h0|(h1<<16); lu[1]=l0|(l1<<16);
    }
    *(uint2*)(dsth + (size_t)token*E_ + e) = make_uint2(hu[0],hu[1]);
    *(uint2*)(dstl + (size_t)token*E_ + e) = make_uint2(lu[0],lu[1]);
}

// ---------------- one-shot fp32 -> hi/lo plane split (qwen) ----------------
__global__ void k_split4(const float* __restrict__ src, unsigned short* __restrict__ hp,
                         unsigned short* __restrict__ lp, int n4){
    int i = blockIdx.x*256 + threadIdx.x;
    if (i >= n4) return;
    float4 v = *(const float4*)(src + i*4);
    unsigned h0,l0,h1,l1,h2,l2,h3,l3;
    sp(v.x,h0,l0); sp(v.y,h1,l1); sp(v.z,h2,l2); sp(v.w,h3,l3);
    *(uint2*)(hp + i*4) = make_uint2(h0|(h1<<16), h2|(h3<<16));
    *(uint2*)(lp + i*4) = make_uint2(l0|(l1<<16), l2|(l3<<16));
}

// ================= split-bf16 MFMA GEMM (round-8 structure: [128][40] LDS, reg dbuf) =================
// A: pre-split row-major bf16 planes. B: fp32 weights, convert on stage.
// EPI: 0 fp32; 1 xt+=g*v; 2 gelu->plane(s) at slot rows; 3 slot fp32 (atomic if SPLITK>1);
//      4 SA-QKV (Q fp32 / K planes / V interleaved); 5 CA-K planes; 6 CA-V interleaved
template<int MOE, int EPI, int GATHER, int TERMS, int SPLITK=1>
__global__ __launch_bounds__(256) void k_mm(
    const unsigned short* __restrict__ Ahpp, const unsigned short* __restrict__ Alpp, int lda,
    const float* __restrict__ Wp, int ldw,
    const float* __restrict__ biasp, int bstride,
    void* __restrict__ Cp, void* __restrict__ Cp2, void* __restrict__ Cp3, void* __restrict__ Cp4,
    int ldc, int M, int N, int K,
    const float* __restrict__ pr, int gch,
    const int* __restrict__ cnt, const int* __restrict__ offs,
    const int* __restrict__ list)
{
    constexpr int NPL = (TERMS==3) ? 2 : 1;
    int e  = MOE ? blockIdx.z : 0;
    int Mm = MOE ? cnt[e] : M;
    int bm = blockIdx.y*128;
    if (MOE && bm >= Mm) return;
    int o0 = MOE ? offs[e] : 0;
    int nt = gridDim.x / SPLITK;
    int ntile = blockIdx.x % nt;
    int kc0 = blockIdx.x / nt;
    int bn = ntile*128;
    int kbeg = kc0*(K/SPLITK), kend = kbeg + K/SPLITK;
    const float* bias = biasp + (size_t)e*bstride;

    __shared__ __align__(16) unsigned short As_[2][NPL][128*40];
    __shared__ __align__(16) unsigned short Bs_[2][NPL][128*40];

    int tid = threadIdx.x;
    int lane = tid & 63, wid = tid >> 6;
    int wm = wid >> 1, wn = wid & 1;

    int srow = tid >> 1, shalf = tid & 1;
    int sbase = srow*40 + shalf*16;
    int amr = bm + srow; if (amr >= Mm) amr = Mm - 1;
    int arow;
    if (MOE) arow = GATHER ? list[o0 + amr] : (o0 + amr);
    else     arow = amr;
    const unsigned short* Ahp = Ahpp + (size_t)arow*lda + shalf*16;
    const unsigned short* Alp = (TERMS==3) ? (Alpp + (size_t)arow*lda + shalf*16) : nullptr;
    const float* Bf = Wp + (size_t)e*N*ldw + (size_t)(bn + srow)*ldw + shalf*16;

    float fB[16];
    uint4 aH0, aH1, aL0, aL1;

    auto LOAD = [&](int k0){
        aH0 = *(const uint4*)(Ahp+k0);
        aH1 = *(const uint4*)(Ahp+k0+8);
        if (TERMS==3){
            aL0 = *(const uint4*)(Alp+k0);
            aL1 = *(const uint4*)(Alp+k0+8);
        }
        *(float4*)(fB+0)  = *(const float4*)(Bf+k0+0);
        *(float4*)(fB+4)  = *(const float4*)(Bf+k0+4);
        *(float4*)(fB+8)  = *(const float4*)(Bf+k0+8);
        *(float4*)(fB+12) = *(const float4*)(Bf+k0+12);
    };
    auto STAGE = [&](int buf){
        *(uint4*)&As_[buf][0][sbase]   = aH0;
        *(uint4*)&As_[buf][0][sbase+8] = aH1;
        if (TERMS==3){
            *(uint4*)&As_[buf][NPL-1][sbase]   = aL0;
            *(uint4*)&As_[buf][NPL-1][sbase+8] = aL1;
        }
        if (TERMS==3){
            unsigned hb2[8], lb2[8];
            #pragma unroll
            for (int i=0;i<8;i++){
                unsigned h0,l0,h1,l1;
                sp(fB[2*i],h0,l0); sp(fB[2*i+1],h1,l1);
                hb2[i]=h0|(h1<<16); lb2[i]=l0|(l1<<16);
            }
            *(uint4*)&Bs_[buf][0][sbase]   = make_uint4(hb2[0],hb2[1],hb2[2],hb2[3]);
            *(uint4*)&Bs_[buf][0][sbase+8] = make_uint4(hb2[4],hb2[5],hb2[6],hb2[7]);
            *(uint4*)&Bs_[buf][NPL-1][sbase]   = make_uint4(lb2[0],lb2[1],lb2[2],lb2[3]);
            *(uint4*)&Bs_[buf][NPL-1][sbase+8] = make_uint4(lb2[4],lb2[5],lb2[6],lb2[7]);
        } else {
            unsigned hb2[8];
            #pragma unroll
            for (int i=0;i<8;i++) hb2[i] = pk2(fB[2*i],fB[2*i+1]);
            *(uint4*)&Bs_[buf][0][sbase]   = make_uint4(hb2[0],hb2[1],hb2[2],hb2[3]);
            *(uint4*)&Bs_[buf][0][sbase+8] = make_uint4(hb2[4],hb2[5],hb2[6],hb2[7]);
        }
    };

    f32x4 acc[4][4];
    #pragma unroll
    for (int m=0;m<4;m++)
        #pragma unroll
        for (int n=0;n<4;n++) acc[m][n] = (f32x4){0.f,0.f,0.f,0.f};

    int fr = lane & 15, fko = (lane>>4)*8, fr4 = (lane>>4)*4;

    LOAD(kbeg);
    STAGE(0);
    __syncthreads();
    int cur = 0;
    for (int k0=kbeg; k0<kend; k0+=32){
        bool nxt = (k0+32) < kend;
        if (nxt) LOAD(k0+32);          // issue next-chunk loads early (hide under MFMA)
        bf16x8 ah[4], bh[4], al[4], bl[4];
        #pragma unroll
        for (int m=0;m<4;m++){
            int off = (wm*64 + m*16 + fr)*40 + fko;
            ah[m] = *(const bf16x8*)&As_[cur][0][off];
            if (TERMS==3) al[m] = *(const bf16x8*)&As_[cur][NPL-1][off];
        }
        #pragma unroll
        for (int n=0;n<4;n++){
            int off = (wn*64 + n*16 + fr)*40 + fko;
            bh[n] = *(const bf16x8*)&Bs_[cur][0][off];
            if (TERMS==3) bl[n] = *(const bf16x8*)&Bs_[cur][NPL-1][off];
        }
        #pragma unroll
        for (int m=0;m<4;m++)
            #pragma unroll
            for (int n=0;n<4;n++){
                acc[m][n] = __builtin_amdgcn_mfma_f32_16x16x32_bf16(ah[m], bh[n], acc[m][n], 0, 0, 0);
                if (TERMS==3){
                    acc[m][n] = __builtin_amdgcn_mfma_f32_16x16x32_bf16(ah[m], bl[n], acc[m][n], 0, 0, 0);
                    acc[m][n] = __builtin_amdgcn_mfma_f32_16x16x32_bf16(al[m], bh[n], acc[m][n], 0, 0, 0);
                }
            }
        if (nxt) STAGE(cur^1);         // write the other buffer after compute
        __syncthreads();
        cur ^= 1;
    }

    #pragma unroll
    for (int m=0;m<4;m++){
        #pragma unroll
        for (int j=0;j<4;j++){
            int row = bm + wm*64 + m*16 + fr4 + j;
            if (row >= Mm) continue;
            #pragma unroll
            for (int n=0;n<4;n++){
                int col = bn + wn*64 + n*16 + fr;
                float bv = (SPLITK==1 || kc0==0) ? bias[col] : 0.f;
                float v = acc[m][n][j] + bv;
                if (EPI==0){
                    ((float*)Cp)[(size_t)row*ldc + col] = v;
                } else if (EPI==1){
                    int bb = row >> 10;
                    ((float*)Cp)[(size_t)row*ldc + col] += pr[bb*9*E_ + gch*E_ + col] * v;
                } else if (EPI==2){
                    size_t pi = (size_t)(o0+row)*ldc + col;
                    if (TERMS==3){
                        unsigned hb, lb; sp(geluf(v), hb, lb);
                        ((unsigned short*)Cp )[pi] = (unsigned short)hb;
                        ((unsigned short*)Cp2)[pi] = (unsigned short)lb;
                    } else {
                        ((unsigned short*)Cp )[pi] = h16(geluf(v));
                    }
                } else if (EPI==3){
                    if (SPLITK==1)
                        ((float*)Cp)[(size_t)(o0+row)*ldc + col] = v;
                    else
                        atomicAdd(&((float*)Cp)[(size_t)(o0+row)*ldc + col], v);
                } else if (EPI==4){
                    if (col < 1024){
                        ((float*)Cp)[(size_t)row*1024 + col] = v;
                    } else {
                        int c2 = col - 1024;
                        int isv = c2 >> 10;
                        int cc = c2 & 1023;
                        int hh2 = cc >> 6, d = cc & 63;
                        size_t idx = (((size_t)(row>>10)*NHEAD + hh2)*1024 + (row & 1023))*64 + d;
                        unsigned hb, lb; sp(v, hb, lb);
                        if (!isv){
                            ((unsigned short*)Cp2)[idx] = (unsigned short)hb;
                            ((unsigned short*)Cp3)[idx] = (unsigned short)lb;
                        } else {
                            ((unsigned*)Cp4)[idx] = hb | (lb<<16);
                        }
                    }
                } else if (EPI==5){
                    int hh2 = col >> 6, d = col & 63;
                    size_t idx = (((size_t)(row>>8)*NHEAD + hh2)*256 + (row & 255))*64 + d;
                    unsigned hb, lb; sp(v, hb, lb);
                    ((unsigned short*)Cp )[idx] = (unsigned short)hb;
                    ((unsigned short*)Cp2)[idx] = (unsigned short)lb;
                } else { // EPI==6
                    int hh2 = col >> 6, d = col & 63;
                    size_t idx = (((size_t)(row>>8)*NHEAD + hh2)*256 + (row & 255))*64 + d;
                    unsigned hb, lb; sp(v, hb, lb);
                    ((unsigned*)Cp)[idx] = hb | (lb<<16);
                }
            }
        }
    }
}

// ================= MFMA flash attention: K/V pre-split, O -> plain row-major planes =================
__global__ __launch_bounds__(256) void k_attn_m(
    const float* __restrict__ qp, int qstride,
    const unsigned short* __restrict__ Khp, const unsigned short* __restrict__ Klp,
    const unsigned* __restrict__ Vip,
    unsigned short* __restrict__ oph, unsigned short* __restrict__ opl,
    int Sq, int Sk, float scale)
{
    __shared__ __align__(16) unsigned short Kh[64*72];
    __shared__ __align__(16) unsigned short Kl[64*72];
    __shared__ __align__(16) unsigned V_i[64*70];
    __shared__ __align__(16) unsigned short P_[4][2][16*72];

    int tid = threadIdx.x, lane = tid & 63, wid = tid >> 6;
    int g = lane >> 4, fr = lane & 15;
    int h = blockIdx.y, b = blockIdx.z;
    int qbase = blockIdx.x*64;
    size_t bhbase = (size_t)(b*NHEAD + h)*Sk*64;

    bf16x8 qh[2], ql[2];
    {
        const float* qr = qp + (size_t)(b*Sq + qbase + wid*16 + fr)*qstride + h*64;
        #pragma unroll
        for (int ds=0; ds<2; ds++){
            float f[8];
            *(float4*)(f+0) = *(const float4*)(qr + ds*32 + g*8);
            *(float4*)(f+4) = *(const float4*)(qr + ds*32 + g*8 + 4);
            U8 uh, ul;
            #pragma unroll
            for (int i=0;i<4;i++){
                unsigned h0,l0,h1,l1;
                sp(f[2*i]*scale, h0,l0); sp(f[2*i+1]*scale, h1,l1);
                uh.u[i] = h0|(h1<<16); ul.u[i] = l0|(l1<<16);
            }
            qh[ds] = uh.v; ql[ds] = ul.v;
        }
    }

    float m_run = -1e30f, l_run = 0.f;
    f32x4 oacc[4];
    #pragma unroll
    for (int dt=0;dt<4;dt++) oacc[dt] = (f32x4){0.f,0.f,0.f,0.f};

    unsigned short* PhW = &P_[wid][0][0];
    unsigned short* PlW = &P_[wid][1][0];

    for (int kt0 = 0; kt0 < Sk; kt0 += 64){
        __syncthreads();
        {
            int srow = tid >> 2, d0 = (tid & 3) << 4;
            size_t gidx = bhbase + (size_t)(kt0 + srow)*64 + d0;
            int base = srow*72 + d0;
            *(uint4*)&Kh[base]   = *(const uint4*)(Khp + gidx);
            *(uint4*)&Kh[base+8] = *(const uint4*)(Khp + gidx + 8);
            *(uint4*)&Kl[base]   = *(const uint4*)(Klp + gidx);
            *(uint4*)&Kl[base+8] = *(const uint4*)(Klp + gidx + 8);
            const unsigned* vsrc = Vip + gidx;
            int vb = srow*70 + d0;
            #pragma unroll
            for (int i4=0;i4<4;i4++){
                uint4 u = *(const uint4*)(vsrc + i4*4);
                *(uint2*)&V_i[vb + i4*4]     = make_uint2(u.x,u.y);
                *(uint2*)&V_i[vb + i4*4 + 2] = make_uint2(u.z,u.w);
            }
        }
        __syncthreads();

        f32x4 st[4];
        #pragma unroll
        for (int kt=0;kt<4;kt++) st[kt] = (f32x4){0.f,0.f,0.f,0.f};
        #pragma unroll
        for (int ds=0; ds<2; ds++){
            #pragma unroll
            for (int kt=0;kt<4;kt++){
                int row = kt*16 + fr;
                int so = row*72 + ds*32 + g*8;
                bf16x8 kh  = *(const bf16x8*)&Kh[so];
                bf16x8 klo = *(const bf16x8*)&Kl[so];
                st[kt] = __builtin_amdgcn_mfma_f32_16x16x32_bf16(kh, qh[ds], st[kt], 0,0,0);
                st[kt] = __builtin_amdgcn_mfma_f32_16x16x32_bf16(kh, ql[ds], st[kt], 0,0,0);
                st[kt] = __builtin_amdgcn_mfma_f32_16x16x32_bf16(klo, qh[ds], st[kt], 0,0,0);
            }
        }

        float pmax = -1e30f;
        #pragma unroll
        for (int kt=0;kt<4;kt++)
            #pragma unroll
            for (int r=0;r<4;r++) pmax = fmaxf(pmax, st[kt][r]);
        pmax = fmaxf(pmax, __shfl_xor(pmax, 16));
        pmax = fmaxf(pmax, __shfl_xor(pmax, 32));
        float mnew = fmaxf(m_run, pmax);
        float p[4][4]; float psum = 0.f;
        #pragma unroll
        for (int kt=0;kt<4;kt++)
            #pragma unroll
            for (int r=0;r<4;r++){ float pv = expf(st[kt][r] - mnew); p[kt][r] = pv; psum += pv; }
        psum += __shfl_xor(psum, 16);
        psum += __shfl_xor(psum, 32);
        float corr = expf(m_run - mnew);
        l_run = l_run*corr + psum;
        m_run = mnew;
        #pragma unroll
        for (int j=0;j<4;j++){
            float cj = __shfl(corr, g*4 + j);
            #pragma unroll
            for (int dt=0;dt<4;dt++) oacc[dt][j] *= cj;
        }

        #pragma unroll
        for (int kt=0;kt<4;kt++){
            unsigned h0,l0,h1,l1,h2,l2,h3,l3;
            sp(p[kt][0],h0,l0); sp(p[kt][1],h1,l1);
            sp(p[kt][2],h2,l2); sp(p[kt][3],h3,l3);
            int base = fr*72 + kt*16 + g*4;
            *(unsigned*)&PhW[base]     = h0|(h1<<16);
            *(unsigned*)&PhW[base + 2] = h2|(h3<<16);
            *(unsigned*)&PlW[base]     = l0|(l1<<16);
            *(unsigned*)&PlW[base + 2] = l2|(l3<<16);
        }

        #pragma unroll
        for (int ks=0; ks<2; ks++){
            int pso = fr*72 + ks*32 + g*8;
            bf16x8 ph = *(const bf16x8*)&PhW[pso];
            bf16x8 pl = *(const bf16x8*)&PlW[pso];
            #pragma unroll
            for (int dt=0; dt<4; dt++){
                unsigned w[8];
                #pragma unroll
                for (int j=0;j<8;j++){
                    int row = ks*32 + g*8 + j;
                    w[j] = V_i[row*70 + dt*16 + fr];
                }
                U8 vh, vl;
                #pragma unroll
                for (int i=0;i<4;i++){
                    vh.u[i] = (w[2*i] & 0xffffu) | (w[2*i+1] << 16);
                    vl.u[i] = (w[2*i] >> 16)     | (w[2*i+1] & 0xffff0000u);
                }
                oacc[dt] = __builtin_amdgcn_mfma_f32_16x16x32_bf16(ph, vh.v, oacc[dt], 0,0,0);
                oacc[dt] = __builtin_amdgcn_mfma_f32_16x16x32_bf16(ph, vl.v, oacc[dt], 0,0,0);
                oacc[dt] = __builtin_amdgcn_mfma_f32_16x16x32_bf16(pl, vh.v, oacc[dt], 0,0,0);
            }
        }
    }

    float linv = 1.f / l_run;
    #pragma unroll
    for (int j=0;j<4;j++){
        float lj = __shfl(linv, g*4 + j);
        int row = qbase + wid*16 + g*4 + j;
        size_t obase = (size_t)(b*Sq + row)*E_ + h*64;
        #pragma unroll
        for (int dt=0;dt<4;dt++){
            unsigned hb, lb; sp(oacc[dt][j]*lj, hb, lb);
            oph[obase + dt*16 + fr] = (unsigned short)hb;
            opl[obase + dt*16 + fr] = (unsigned short)lb;
        }
    }
}

// ---------------- MoE routing ----------------
__global__ void k_route(const float* __restrict__ xn, const float* __restrict__ gw,
                        const float* __restrict__ gb, int* __restrict__ i01,
                        float* __restrict__ w01, int* __restrict__ cnt){
    int token = blockIdx.x, lane = threadIdx.x;
    const float* row = xn + (size_t)token*E_;
    float part[8] = {0,0,0,0,0,0,0,0};
    for (int k = lane; k < E_; k += 64){
        float xv = row[k];
        #pragma unroll
        for (int e=0;e<8;e++) part[e] += xv*gw[e*E_+k];
    }
    #pragma unroll
    for (int e=0;e<8;e++){
        #pragma unroll
        for (int off=32; off; off>>=1) part[e] += __shfl_down(part[e], off);
    }
    if (lane==0){
        float lg[8]; float mx = -1e30f;
        #pragma unroll
        for (int e=0;e<8;e++){ lg[e] = part[e]+gb[e]; if (lg[e]>mx) mx = lg[e]; }
        float sum = 0.f;
        #pragma unroll
        for (int e=0;e<8;e++){ lg[e] = expf(lg[e]-mx); sum += lg[e]; }
        int a0 = 0;
        #pragma unroll
        for (int e=1;e<8;e++) if (lg[e] > lg[a0]) a0 = e;
        int a1 = (a0==0)?1:0;
        #pragma unroll
        for (int e=0;e<8;e++) if (e!=a0 && lg[e] > lg[a1]) a1 = e;
        float p0 = lg[a0]/sum, p1 = lg[a1]/sum;
        float inv = 1.f/(p0+p1+1e-6f);
        i01[token*2+0]=a0; i01[token*2+1]=a1;
        w01[token*2+0]=p0*inv; w01[token*2+1]=p1*inv;
        atomicAdd(&cnt[a0],1); atomicAdd(&cnt[a1],1);
    }
}

__global__ void k_scan(const int* __restrict__ cnt, int* __restrict__ offs, int* __restrict__ curs){
    if (threadIdx.x==0 && blockIdx.x==0){
        int o = 0;
        for (int e=0;e<8;e++){ offs[e]=o; curs[e]=o; o += cnt[e]; }
    }
}

__global__ void k_place(const int* __restrict__ i01,
                        int* __restrict__ curs, int* __restrict__ list,
                        int* __restrict__ t2s){
    int t = blockIdx.x*256 + threadIdx.x;
    if (t >= TOK) return;
    #pragma unroll
    for (int s=0;s<2;s++){
        int e = i01[t*2+s];
        int p = atomicAdd(&curs[e],1);
        list[p] = t;
        t2s[t*2+s] = p;
    }
}

__global__ void k_moe_combine2(float* __restrict__ xt, const float* __restrict__ yslot,
                               const int* __restrict__ t2s, const float* __restrict__ w01,
                               const float* __restrict__ pr){
    int idx = blockIdx.x*256 + threadIdx.x;
    int token = idx >> 10, n = idx & 1023;
    int b = token >> 10;
    int s0 = t2s[token*2], s1 = t2s[token*2+1];
    float mo = w01[token*2]*yslot[(size_t)s0*E_+n] + w01[token*2+1]*yslot[(size_t)s1*E_+n];
    xt[idx] += pr[b*9*E_ + 8*E_ + n]*mo;
}

// ---------------- final LN + projection + unpatchify ----------------
__global__ void k_final(const float* __restrict__ xt, const float* __restrict__ fw,
                        const float* __restrict__ fb, float* __restrict__ out){
    int token = blockIdx.x, tid = threadIdx.x;
    int b = token >> 10, n = token & 1023, hh = n >> 5, ww = n & 31;
    const float* row = xt + (size_t)token*E_;
    float4 v = *(const float4*)(row + tid*4);
    float s = v.x+v.y+v.z+v.w;
    float ss = v.x*v.x+v.y*v.y+v.z*v.z+v.w*v.w;
    #pragma unroll
    for (int off=32; off; off>>=1){ s += __shfl_down(s,off); ss += __shfl_down(ss,off); }
    __shared__ float rs_[4], rss_[4];
    int wid = tid >> 6;
    if ((tid&63)==0){ rs_[wid]=s; rss_[wid]=ss; }
    __syncthreads();
    s  = rs_[0]+rs_[1]+rs_[2]+rs_[3];
    ss = rss_[0]+rss_[1]+rss_[2]+rss_[3];
    float mean = s*(1.f/1024.f);
    float rstd = rsqrtf(ss*(1.f/1024.f) - mean*mean + 1e-6f);
    __shared__ float xl[1024];
    int e = tid*4;
    xl[e+0]=(v.x-mean)*rstd; xl[e+1]=(v.y-mean)*rstd;
    xl[e+2]=(v.z-mean)*rstd; xl[e+3]=(v.w-mean)*rstd;
    __syncthreads();
    int o = tid & 15, seg = tid >> 4;
    float part = 0.f;
    const float* wr = fw + (size_t)o*E_ + seg*64;
    const float* xr = xl + seg*64;
    #pragma unroll 8
    for (int j=0;j<64;j++) part += xr[j]*wr[j];
    __shared__ float ps[16][17];
    ps[seg][o] = part;
    __syncthreads();
    if (tid < 16){
        float acc = fb[tid];
        #pragma unroll
        for (int s2=0;s2<16;s2++) acc += ps[s2][tid];
        int py = tid>>3, px = (tid>>2)&1, ch = tid&3;
        out[(((size_t)b*4+ch)*64 + hh*2+py)*64 + ww*2+px] = acc;
    }
}

extern "C" void kernel_launch(void* const* d_in, const int* in_sizes, int n_in,
                              void* d_out, int out_size, void* d_ws, size_t ws_size,
                              hipStream_t stream){
    const float* x        = (const float*)d_in[0];
    const float* t        = (const float*)d_in[1];
    const float* clip     = (const float*)d_in[2];
    const float* qwen     = (const float*)d_in[3];
    const float* conv_w   = (const float*)d_in[4];
    const float* conv_b   = (const float*)d_in[5];
    const float* pos      = (const float*)d_in[6];
    const float* tw1      = (const float*)d_in[7];
    const float* tb1      = (const float*)d_in[8];
    const float* tw2      = (const float*)d_in[9];
    const float* tb2      = (const float*)d_in[10];
    const float* cond_w   = (const float*)d_in[11];
    const float* cond_b   = (const float*)d_in[12];
    const float* ada_w    = (const float*)d_in[13];
    const float* ada_b    = (const float*)d_in[14];
    const float* sa_in_w  = (const float*)d_in[15];
    const float* sa_in_b  = (const float*)d_in[16];
    const float* sa_out_w = (const float*)d_in[17];
    const float* sa_out_b = (const float*)d_in[18];
    const float* ca_q_w   = (const float*)d_in[19];
    const float* ca_k_w   = (const float*)d_in[20];
    const float* ca_v_w   = (const float*)d_in[21];
    const float* ca_in_b  = (const float*)d_in[22];
    const float* ca_out_w = (const float*)d_in[23];
    const float* ca_out_b = (const float*)d_in[24];
    const float* gate_w   = (const float*)d_in[25];
    const float* gate_b   = (const float*)d_in[26];
    const float* e_w1     = (const float*)d_in[27];
    const float* e_b1     = (const float*)d_in[28];
    const float* e_w2     = (const float*)d_in[29];
    const float* e_b2     = (const float*)d_in[30];
    const float* fin_w    = (const float*)d_in[31];
    const float* fin_b    = (const float*)d_in[32];

    float* ws    = (float*)d_ws;
    float* xt    = ws;                                         // 2M floats
    float* xn    = ws + 2097152;                               // 2M
    float* qbuf  = ws + 4194304;                               // 2M fp32 (attn Q)
    unsigned short* Khp = (unsigned short*)(ws + 6291456);     // 2M shorts
    unsigned short* Klp = (unsigned short*)(ws + 7340032);
    unsigned*       Vip = (unsigned*)(ws + 8388608);           // 2M u32
    float* yslot = ws + 4194304;                               // MoE phase reuse (4M floats)
    unsigned short* xnh  = (unsigned short*)(ws + 10485760);
    unsigned short* xnl  = (unsigned short*)(ws + 11534336);
    unsigned short* obh  = (unsigned short*)(ws + 12582912);
    unsigned short* obl  = (unsigned short*)(ws + 13631488);
    unsigned short* hidh = (unsigned short*)(ws + 14680064);   // 8M floats region
    unsigned short* hidl = (unsigned short*)(ws + 23068672);
    unsigned short* qwh  = (unsigned short*)(ws + 31457280);
    unsigned short* qwl  = (unsigned short*)(ws + 31981568);
    float* pr    = ws + 33554432;
    float* sic   = ws + 33572864;
    float* w01   = ws + 33574912;
    int*   i01   = (int*)(ws + 33579008);
    int*   t2s   = (int*)(ws + 33583104);
    int*   list  = (int*)(ws + 33587200);
    int*   cnt   = (int*)(ws + 33591296);
    int*   offs  = cnt + 8;
    int*   curs  = cnt + 16;
    float* te2g  = ws + 33591808;

    k_patch_embed<<<TOK,256,0,stream>>>(x, conv_w, conv_b, pos, xt);
    k_time_mlp<<<B_,256,0,stream>>>(t, tw1, tb1, tw2, tb2, te2g);
    k_cond<<<512,256,0,stream>>>(te2g, clip, cond_w, cond_b, sic);
    k_split4<<<(B_*256*KD/4+255)/256,256,0,stream>>>(qwen, qwh, qwl, B_*256*KD/4);

    for (int i=0;i<2;i++){
        k_ada2<<<2304,256,0,stream>>>(sic, ada_w + (size_t)i*9*E_*E_,
                                      ada_b + (size_t)i*9*E_, pr);
        // ---- self-attention ----
        k_ln_mod<<<TOK,256,0,stream>>>(xt, nullptr, xnh, xnl, pr, 0, 1);
        k_mm<0,4,0,3><<<dim3(24,16),256,0,stream>>>(
            xnh, xnl, E_, sa_in_w + (size_t)i*3*E_*E_, E_, sa_in_b + (size_t)i*3*E_, 0,
            qbuf, Khp, Klp, Vip, 0, TOK, 3*E_, E_, nullptr, 0, nullptr, nullptr, nullptr);
        k_attn_m<<<dim3(16,NHEAD,B_),256,0,stream>>>(qbuf, 1024, Khp, Klp, Vip,
                                                     obh, obl, S_, S_, 0.125f);
        k_mm<0,1,0,3><<<dim3(8,16),256,0,stream>>>(
            obh, obl, E_, sa_out_w + (size_t)i*E_*E_, E_, sa_out_b + (size_t)i*E_, 0,
            xt, nullptr, nullptr, nullptr, E_, TOK, E_, E_, pr, 2, nullptr, nullptr, nullptr);
        // ---- cross-attention ----
        k_ln_mod<<<TOK,256,0,stream>>>(xt, nullptr, xnh, xnl, pr, 3, 4);
        k_mm<0,0,0,3><<<dim3(8,16),256,0,stream>>>(
            xnh, xnl, E_, ca_q_w + (size_t)i*E_*E_, E_, ca_in_b + (size_t)i*3*E_, 0,
            qbuf, nullptr, nullptr, nullptr, E_, TOK, E_, E_, nullptr, 0, nullptr, nullptr, nullptr);
        k_mm<0,5,0,3><<<dim3(8,4),256,0,stream>>>(
            qwh, qwl, KD, ca_k_w + (size_t)i*E_*KD, KD, ca_in_b + (size_t)i*3*E_ + E_, 0,
            Khp, Klp, nullptr, nullptr, 0, B_*256, E_, KD, nullptr, 0, nullptr, nullptr, nullptr);
        k_mm<0,6,0,3><<<dim3(8,4),256,0,stream>>>(
            qwh, qwl, KD, ca_v_w + (size_t)i*E_*KD, KD, ca_in_b + (size_t)i*3*E_ + 2*E_, 0,
            Vip, nullptr, nullptr, nullptr, 0, B_*256, E_, KD, nullptr, 0, nullptr, nullptr, nullptr);
        k_attn_m<<<dim3(16,NHEAD,B_),256,0,stream>>>(qbuf, E_, Khp, Klp, Vip,
                                                     obh, obl, S_, 256, 0.125f);
        k_mm<0,1,0,3><<<dim3(8,16),256,0,stream>>>(
            obh, obl, E_, ca_out_w + (size_t)i*E_*E_, E_, ca_out_b + (size_t)i*E_, 0,
            xt, nullptr, nullptr, nullptr, E_, TOK, E_, E_, pr, 5, nullptr, nullptr, nullptr);
        // ---- MoE ----
        k_ln_mod<<<TOK,256,0,stream>>>(xt, xn, xnh, xnl, pr, 6, 7);
        hipMemsetAsync(cnt, 0, 8*sizeof(int), stream);
        k_route<<<TOK,64,0,stream>>>(xn, gate_w + (size_t)i*NE*E_, gate_b + (size_t)i*NE,
                                     i01, w01, cnt);
        k_scan<<<1,64,0,stream>>>(cnt, offs, curs);
        k_place<<<TOK/256,256,0,stream>>>(i01, curs, list, t2s);
        hipMemsetAsync(yslot, 0, (size_t)2*TOK*E_*sizeof(float), stream);
        if (i==0){
            k_mm<1,2,1,3><<<dim3(32,32,NE),256,0,stream>>>(
                xnh, xnl, E_, e_w1 + (size_t)i*NE*II*E_, E_, e_b1 + (size_t)i*NE*II, II,
                hidh, hidl, nullptr, nullptr, II, 0, II, E_, nullptr, 0, cnt, offs, list);
            k_mm<1,3,0,3,4><<<dim3(32,32,NE),256,0,stream>>>(
                hidh, hidl, II, e_w2 + (size_t)i*NE*E_*II, II, e_b2 + (size_t)i*NE*E_, E_,
                yslot, nullptr, nullptr, nullptr, E_, 0, E_, II, nullptr, 0, cnt, offs, nullptr);
        } else {
            k_mm<1,2,1,1><<<dim3(32,32,NE),256,0,stream>>>(
                xnh, nullptr, E_, e_w1 + (size_t)i*NE*II*E_, E_, e_b1 + (size_t)i*NE*II, II,
                hidh, nullptr, nullptr, nullptr, II, 0, II, E_, nullptr, 0, cnt, offs, list);
            k_mm<1,3,0,1,4><<<dim3(32,32,NE),256,0,stream>>>(
                hidh, nullptr, II, e_w2 + (size_t)i*NE*E_*II, II, e_b2 + (size_t)i*NE*E_, E_,
                yslot, nullptr, nullptr, nullptr, E_, 0, E_, II, nullptr, 0, cnt, offs, nullptr);
        }
        k_moe_combine2<<<TOK*E_/256,256,0,stream>>>(xt, yslot, t2s, w01, pr);
    }
    k_final<<<TOK,256,0,stream>>>(xt, fin_w, fin_b, (float*)d_out);
}